// Round 8
// baseline (427.286 us; speedup 1.0000x reference)
//
#include <hip/hip_runtime.h>
#include <cstdint>
#include <cstddef>

typedef __bf16 bf16x8 __attribute__((ext_vector_type(8)));
typedef __bf16 bf16x4 __attribute__((ext_vector_type(4)));
typedef float f32x4 __attribute__((ext_vector_type(4)));

// ---------------------------------------------------------------------------
// Problem constants (B=1): D=2048, NH=16, DH=128, DC=512, DCQ=1024, L=2048
// ---------------------------------------------------------------------------

// ---------------------------------------------------------------------------
// MFMA GEMM core: C(M,N) = A(M,K) @ Bt(N,K)^T.  A,Bt row-major bf16.
// 128x128 tile, BK=32, 4 waves, each wave 64x64 (4x4 of 16x16x32 MFMA).
// ---------------------------------------------------------------------------
template <bool BF16OUT>
__device__ __forceinline__ void gemm_body(const __bf16* __restrict__ A,
                                          const __bf16* __restrict__ Bt,
                                          void* __restrict__ Cv,
                                          int N, int K, int bm, int bn,
                                          __bf16* As, __bf16* Bs) {
  const int tid = threadIdx.x;
  const int w = tid >> 6;
  const int lane = tid & 63;
  const int quad = lane >> 4;
  const int l16 = lane & 15;
  const int wm = (w & 1) * 64;
  const int wn = (w >> 1) * 64;
  const int srow = lane >> 2;
  const int sseg = (lane & 3) * 8;

  f32x4 acc[4][4];
#pragma unroll
  for (int i = 0; i < 4; ++i)
#pragma unroll
    for (int j = 0; j < 4; ++j) acc[i][j] = (f32x4){0.f, 0.f, 0.f, 0.f};

  for (int k0 = 0; k0 < K; k0 += 32) {
    __syncthreads();
#pragma unroll
    for (int g = 0; g < 2; ++g) {
      const int grp = w + g * 4;
      const __bf16* ga = A + (size_t)(bm + grp * 16 + srow) * K + k0 + sseg;
      const __bf16* gb = Bt + (size_t)(bn + grp * 16 + srow) * K + k0 + sseg;
      __builtin_amdgcn_global_load_lds(
          (const __attribute__((address_space(1))) void*)ga,
          (__attribute__((address_space(3))) void*)&As[grp * 512], 16, 0, 0);
      __builtin_amdgcn_global_load_lds(
          (const __attribute__((address_space(1))) void*)gb,
          (__attribute__((address_space(3))) void*)&Bs[grp * 512], 16, 0, 0);
    }
    __syncthreads();
    bf16x8 af[4], bfr[4];
#pragma unroll
    for (int i = 0; i < 4; ++i) {
      af[i] = *(const bf16x8*)&As[(wm + i * 16 + l16) * 32 + quad * 8];
      bfr[i] = *(const bf16x8*)&Bs[(wn + i * 16 + l16) * 32 + quad * 8];
    }
#pragma unroll
    for (int i = 0; i < 4; ++i)
#pragma unroll
      for (int j = 0; j < 4; ++j)
        acc[i][j] = __builtin_amdgcn_mfma_f32_16x16x32_bf16(af[i], bfr[j],
                                                            acc[i][j], 0, 0, 0);
  }
#pragma unroll
  for (int i = 0; i < 4; ++i)
#pragma unroll
    for (int j = 0; j < 4; ++j)
#pragma unroll
      for (int r = 0; r < 4; ++r) {
        const int row = bm + wm + i * 16 + quad * 4 + r;
        const int col = bn + wn + j * 16 + l16;
        if constexpr (BF16OUT)
          ((__bf16*)Cv)[(size_t)row * N + col] = (__bf16)acc[i][j][r];
        else
          ((float*)Cv)[(size_t)row * N + col] = acc[i][j][r];
      }
}

template <bool BF16OUT>
__global__ __launch_bounds__(256) void gemm_mfma(const __bf16* __restrict__ A,
                                                 const __bf16* __restrict__ Bt,
                                                 void* __restrict__ Cv,
                                                 int M, int N, int K) {
  __shared__ __bf16 As[128 * 32];
  __shared__ __bf16 Bs[128 * 32];
  gemm_body<BF16OUT>(A, Bt, Cv, N, K, blockIdx.y * 128, blockIdx.x * 128, As, Bs);
}

// Up to 3 independent GEMMs fused by blockIdx.x ranges.
__global__ __launch_bounds__(256) void gemm_fused3(
    const __bf16* A0, const __bf16* B0, __bf16* C0, int N0, int K0, int nx0,
    const __bf16* A1, const __bf16* B1, __bf16* C1, int N1, int K1, int nx1,
    const __bf16* A2, const __bf16* B2, __bf16* C2, int N2, int K2) {
  __shared__ __bf16 As[128 * 32];
  __shared__ __bf16 Bs[128 * 32];
  const int bx = blockIdx.x;
  const __bf16 *A, *Bt;
  __bf16* C;
  int N, K, bxl;
  if (bx < nx0)            { A = A0; Bt = B0; C = C0; N = N0; K = K0; bxl = bx; }
  else if (bx < nx0 + nx1) { A = A1; Bt = B1; C = C1; N = N1; K = K1; bxl = bx - nx0; }
  else                     { A = A2; Bt = B2; C = C2; N = N2; K = K2; bxl = bx - nx0 - nx1; }
  gemm_body<true>(A, Bt, (void*)C, N, K, blockIdx.y * 128, bxl * 128, As, Bs);
}

// ---------------------------------------------------------------------------
// prep_all: all weight transposes (fp32 (K,N) -> bf16 (N,K), 32x32 tiles),
// x cast, rope tables, W_lam transpose — one launch.
// ---------------------------------------------------------------------------
__global__ __launch_bounds__(256) void prep_all(
    const float* __restrict__ W_DKV, const float* __restrict__ W_DQ,
    const float* __restrict__ W_UK,  const float* __restrict__ W_UV,
    const float* __restrict__ W_UQ,  const float* __restrict__ W_out,
    const float* __restrict__ x,     const float* __restrict__ W_lam,
    __bf16* __restrict__ tDKV, __bf16* __restrict__ tDQ,
    __bf16* __restrict__ tUK,  __bf16* __restrict__ tUV,
    __bf16* __restrict__ tUQ,  __bf16* __restrict__ tOut,
    __bf16* __restrict__ x_bf, __bf16* __restrict__ WlT,
    float* __restrict__ cosT, float* __restrict__ sinT) {
  __shared__ float T[32][36];
  int t = blockIdx.x;
  const int tid = threadIdx.x;
  if (t < 13312) {
    const float* src; __bf16* dst; int K, N, kx, ny;
    if (t < 1024)      {            src = W_DKV; dst = tDKV; K = 2048; N = 512;  kx = t & 63; ny = t >> 6; }
    else if (t < 3072) { t -= 1024; src = W_DQ;  dst = tDQ;  K = 2048; N = 1024; kx = t & 63; ny = t >> 6; }
    else if (t < 4096) { t -= 3072; src = W_UK;  dst = tUK;  K = 512;  N = 2048; kx = t & 15; ny = t >> 4; }
    else if (t < 5120) { t -= 4096; src = W_UV;  dst = tUV;  K = 512;  N = 2048; kx = t & 15; ny = t >> 4; }
    else if (t < 9216) { t -= 5120; src = W_UQ;  dst = tUQ;  K = 1024; N = 4096; kx = t & 31; ny = t >> 5; }
    else               { t -= 9216; src = W_out; dst = tOut; K = 2048; N = 2048; kx = t & 63; ny = t >> 6; }
    const int k0 = kx * 32;
    const int n0 = ny * 32;
    const int r = tid >> 3;
    const int c = (tid & 7) * 4;
    *(float4*)&T[r][c] = *(const float4*)&src[(size_t)(k0 + r) * N + n0 + c];
    __syncthreads();
    bf16x4 o = {(__bf16)T[c + 0][r], (__bf16)T[c + 1][r],
                (__bf16)T[c + 2][r], (__bf16)T[c + 3][r]};
    *(bf16x4*)&dst[(size_t)(n0 + r) * K + k0 + c] = o;
    return;
  }
  t -= 13312;
  if (t < 4096) {  // x cast: 4096 blocks x 1024 floats
    const int i = t * 256 + tid;
    float4 v = *(const float4*)&x[(size_t)i * 4];
    bf16x4 o = {(__bf16)v.x, (__bf16)v.y, (__bf16)v.z, (__bf16)v.w};
    *(bf16x4*)&x_bf[(size_t)i * 4] = o;
    return;
  }
  t -= 4096;
  if (t < 1024) {  // rope tables: 2 rows per block
    const int l = t * 2 + (tid >> 7);
    const int d = tid & 127;
    const int j = d & 63;
    const float inv = exp2f(-(float)j * 0.2076205059304601f);  // log2(1e4)/64
    const float ang = (float)l * inv;
    cosT[l * 128 + d] = cosf(ang);
    sinT[l * 128 + d] = sinf(ang);
    return;
  }
  t -= 1024;
  {  // W_lam (2048,16) -> WlT (16,2048) bf16: 128 blocks
    const int i = t * 256 + tid;
    const int k = i >> 4, n = i & 15;
    WlT[(size_t)n * 2048 + k] = (__bf16)W_lam[i];
  }
}

// ---------------------------------------------------------------------------
// ropek_transv: K-RoPE (in place) + V transpose, one launch.
// ---------------------------------------------------------------------------
__global__ __launch_bounds__(256) void ropek_transv(__bf16* __restrict__ k_bf,
                                                    const float* __restrict__ cosT,
                                                    const float* __restrict__ sinT,
                                                    const __bf16* __restrict__ v_bf,
                                                    __bf16* __restrict__ v_t) {
  __shared__ float row[2048];
  __shared__ __align__(16) __bf16 Ts[32][40];
  int t = blockIdx.x;
  const int tid = threadIdx.x;
  if (t < 2048) {  // rope row t of k_bf (W=2048)
    __bf16* rp = k_bf + (size_t)t * 2048;
#pragma unroll
    for (int i = 0; i < 2; ++i) {
      const int e4 = (tid + 256 * i) * 4;
      bf16x4 v = *(const bf16x4*)&rp[e4];
#pragma unroll
      for (int k = 0; k < 4; ++k) row[e4 + k] = (float)v[k];
    }
    __syncthreads();
#pragma unroll
    for (int i = 0; i < 8; ++i) {
      const int e = tid + 256 * i;
      const int d = e & 127;
      const float c = cosT[t * 128 + d];
      const float s = sinT[t * 128 + d];
      const float tv = row[e];
      const int base = e & ~127;
      const float rot = (d < 64) ? -row[base + d + 64] : row[base + d - 64];
      rp[e] = (__bf16)(tv * c + rot * s);
    }
    return;
  }
  t -= 2048;
  const int l0 = (t & 63) * 32;
  const int d0 = (t >> 6) * 32;
  const int r = tid >> 3;
  const int c = (tid & 7) * 4;
  *(bf16x4*)&Ts[r][c] = *(const bf16x4*)&v_bf[(size_t)(l0 + r) * 2048 + d0 + c];
  __syncthreads();
  bf16x4 o = {Ts[c + 0][r], Ts[c + 1][r], Ts[c + 2][r], Ts[c + 3][r]};
  *(bf16x4*)&v_t[(size_t)(d0 + r) * 2048 + l0 + c] = o;
}

// lam(l,h) = sigmoid(x_bf[l,:] . W_lam[:,h] + b_lam[h]) via MFMA (N=16).
__global__ __launch_bounds__(256) void lam_mfma_kernel(const __bf16* __restrict__ x_bf,
                                                       const __bf16* __restrict__ WlT,
                                                       const float* __restrict__ b_lam,
                                                       float* __restrict__ lam) {
  const int tid = threadIdx.x;
  const int w = tid >> 6, lane = tid & 63, quad = lane >> 4, l16 = lane & 15;
  const int m0 = (blockIdx.x * 4 + w) * 16;
  const __bf16* xrow = x_bf + (size_t)(m0 + l16) * 2048 + quad * 8;
  const __bf16* wrow = WlT + (size_t)l16 * 2048 + quad * 8;
  f32x4 acc[4];
#pragma unroll
  for (int u = 0; u < 4; ++u) acc[u] = (f32x4){0.f, 0.f, 0.f, 0.f};
  for (int k0 = 0; k0 < 2048; k0 += 128) {
#pragma unroll
    for (int u = 0; u < 4; ++u) {
      bf16x8 a = *(const bf16x8*)&xrow[k0 + u * 32];
      bf16x8 b = *(const bf16x8*)&wrow[k0 + u * 32];
      acc[u] = __builtin_amdgcn_mfma_f32_16x16x32_bf16(a, b, acc[u], 0, 0, 0);
    }
  }
  const float bl = b_lam[l16];
#pragma unroll
  for (int r = 0; r < 4; ++r) {
    const float v = acc[0][r] + acc[1][r] + acc[2][r] + acc[3][r] + bl;
    lam[(size_t)(m0 + quad * 4 + r) * 16 + l16] = 1.0f / (1.0f + __expf(-v));
  }
}

// ---------------------------------------------------------------------------
// MFMA flash attention + fused differential combine.
//  Block = (kv-head hk, 64 q-rows). Waves 0,1 -> q-head 2hk rows [0..31],[32..63];
//  waves 2,3 -> q-head 2hk+1 same rows (share K/V). K-tile 64.
//  K/V fragments read DIRECTLY from global (L1/L2-hot) — no LDS staging,
//  no barriers in the k-loop. P in per-wave LDS. Q-RoPE+scale fused.
//  Epilogue: waves 2,3 push inv-scaled O to LDS; waves 0,1 write
//  y[l, hk*128+d] = O1 - lam*O2 directly (combine fused).
// ---------------------------------------------------------------------------
__global__ __launch_bounds__(256, 2) void attn_kernel2(
    const __bf16* __restrict__ Qb, const __bf16* __restrict__ Kb,
    const __bf16* __restrict__ Vt, const float* __restrict__ cosT,
    const float* __restrict__ sinT, const float* __restrict__ lam,
    __bf16* __restrict__ y) {
  __shared__ __align__(16) char smem[33792];
  __bf16 (*Ps)[32][72] = (__bf16(*)[32][72])smem;   // [4][32][72] during loop
  float (*Ex)[132] = (float(*)[132])smem;           // [64][132] in epilogue

  const int bx = blockIdx.x;
  const int hv = bx >> 8;
  const int ii = bx & 255;
  const int qt = hv ? (ii >> 4) : 31 - (ii >> 4);   // heavy/light pairing
  const int hk = ii & 15;
  const int q0 = qt * 64;
  const int tid = threadIdx.x;
  const int w = tid >> 6, lane = tid & 63, quad = lane >> 4, l16 = lane & 15;
  const int wrow = (w & 1) * 32;
  const int qoff = (2 * hk + (w >> 1)) * 128;
  const int kvoff = hk * 128;
  const float qscale = 0.08838834764831845f;  // 1/sqrt(128), folded into Q

  // ---- Q fragments + RoPE + scale in-register ----
  bf16x8 aq[2][4];
#pragma unroll
  for (int s = 0; s < 2; ++s) {
    const int l = q0 + wrow + s * 16 + l16;
    const size_t qbase = (size_t)l * 4096 + qoff + quad * 8;
    bf16x8 raw[4];
#pragma unroll
    for (int ks = 0; ks < 4; ++ks)
      raw[ks] = *(const bf16x8*)&Qb[qbase + ks * 32];
#pragma unroll
    for (int ks = 0; ks < 4; ++ks) {
      const float* cp = &cosT[l * 128 + ks * 32 + quad * 8];
      const float* sp = &sinT[l * 128 + ks * 32 + quad * 8];
#pragma unroll
      for (int j = 0; j < 8; ++j) {
        const float cv = cp[j];
        const float sv = sp[j];
        const float rot = (ks < 2) ? -(float)raw[ks + 2][j] : (float)raw[ks - 2][j];
        aq[s][ks][j] = (__bf16)(((float)raw[ks][j] * cv + rot * sv) * qscale);
      }
    }
  }

  f32x4 o[2][8];
#pragma unroll
  for (int s = 0; s < 2; ++s)
#pragma unroll
    for (int i = 0; i < 8; ++i) o[s][i] = (f32x4){0.f, 0.f, 0.f, 0.f};
  float m[2] = {-1e30f, -1e30f}, lsum[2] = {0.f, 0.f};

  for (int kt = 0; kt <= qt; ++kt) {
    const int k0 = kt * 64;
    // ---- S^T = K Q^T, K fragments straight from global ----
    f32x4 st[2][4];
#pragma unroll
    for (int s = 0; s < 2; ++s)
#pragma unroll
      for (int t = 0; t < 4; ++t) st[s][t] = (f32x4){0.f, 0.f, 0.f, 0.f};
#pragma unroll
    for (int ks = 0; ks < 4; ++ks) {
#pragma unroll
      for (int t = 0; t < 4; ++t) {
        bf16x8 ak = *(const bf16x8*)&Kb[(size_t)(k0 + t * 16 + l16) * 2048 +
                                        kvoff + ks * 32 + quad * 8];
        st[0][t] = __builtin_amdgcn_mfma_f32_16x16x32_bf16(ak, aq[0][ks], st[0][t], 0, 0, 0);
        st[1][t] = __builtin_amdgcn_mfma_f32_16x16x32_bf16(ak, aq[1][ks], st[1][t], 0, 0, 0);
      }
    }
    // ---- online softmax (scale pre-folded into Q) ----
    const bool masked = (kt == qt);
#pragma unroll
    for (int s = 0; s < 2; ++s) {
      const int q = q0 + wrow + s * 16 + l16;
      float rm = -1e30f;
      if (!masked) {
#pragma unroll
        for (int t = 0; t < 4; ++t)
#pragma unroll
          for (int r = 0; r < 4; ++r) rm = fmaxf(rm, st[s][t][r]);
      } else {
#pragma unroll
        for (int t = 0; t < 4; ++t)
#pragma unroll
          for (int r = 0; r < 4; ++r) {
            const int key = k0 + t * 16 + quad * 4 + r;
            if (key > q) st[s][t][r] = -1e30f;
            rm = fmaxf(rm, st[s][t][r]);
          }
      }
      rm = fmaxf(rm, __shfl_xor(rm, 16, 64));
      rm = fmaxf(rm, __shfl_xor(rm, 32, 64));
      const float mn = fmaxf(m[s], rm);
      const float alpha = __expf(m[s] - mn);
      float rs = 0.f;
#pragma unroll
      for (int t = 0; t < 4; ++t)
#pragma unroll
        for (int r = 0; r < 4; ++r) {
          st[s][t][r] = __expf(st[s][t][r] - mn);
          rs += st[s][t][r];
        }
      rs += __shfl_xor(rs, 16, 64);
      rs += __shfl_xor(rs, 32, 64);
      m[s] = mn;
      lsum[s] = lsum[s] * alpha + rs;
#pragma unroll
      for (int t = 0; t < 4; ++t) {
        bf16x4 pk = {(__bf16)st[s][t][0], (__bf16)st[s][t][1],
                     (__bf16)st[s][t][2], (__bf16)st[s][t][3]};
        *(bf16x4*)&Ps[w][s * 16 + l16][t * 16 + quad * 4] = pk;
      }
#pragma unroll
      for (int r = 0; r < 4; ++r) {
        const float ar = __shfl(alpha, quad * 4 + r, 64);
#pragma unroll
        for (int nt = 0; nt < 8; ++nt) o[s][nt][r] *= ar;
      }
    }
    // ---- O += P V : P from per-wave LDS, V fragments straight from global ----
#pragma unroll
    for (int ks = 0; ks < 2; ++ks) {
      bf16x8 pa0 = *(bf16x8*)&Ps[w][l16][ks * 32 + quad * 8];
      bf16x8 pa1 = *(bf16x8*)&Ps[w][16 + l16][ks * 32 + quad * 8];
#pragma unroll
      for (int nt = 0; nt < 8; ++nt) {
        bf16x8 bv = *(const bf16x8*)&Vt[(size_t)(kvoff + nt * 16 + l16) * 2048 +
                                        k0 + ks * 32 + quad * 8];
        o[0][nt] = __builtin_amdgcn_mfma_f32_16x16x32_bf16(pa0, bv, o[0][nt], 0, 0, 0);
        o[1][nt] = __builtin_amdgcn_mfma_f32_16x16x32_bf16(pa1, bv, o[1][nt], 0, 0, 0);
      }
    }
  }
  // ---- epilogue: fused differential combine ----
  __syncthreads();  // all waves done with Ps; smem becomes Ex
  if (w >= 2) {     // q-head 2hk+1: publish inv-scaled O
#pragma unroll
    for (int s = 0; s < 2; ++s) {
      const float linv = 1.0f / lsum[s];
#pragma unroll
      for (int r = 0; r < 4; ++r) {
        const float inv = __shfl(linv, quad * 4 + r, 64);
        const int rr = wrow + s * 16 + quad * 4 + r;
#pragma unroll
        for (int nt = 0; nt < 8; ++nt)
          Ex[rr][nt * 16 + l16] = o[s][nt][r] * inv;
      }
    }
  }
  __syncthreads();
  if (w < 2) {      // q-head 2hk: combine and write y
#pragma unroll
    for (int s = 0; s < 2; ++s) {
      const float linv = 1.0f / lsum[s];
#pragma unroll
      for (int r = 0; r < 4; ++r) {
        const float inv = __shfl(linv, quad * 4 + r, 64);
        const int rr = wrow + s * 16 + quad * 4 + r;
        const int l = q0 + rr;
        const float lm = lam[l * 16 + hk];
        __bf16* dst = y + (size_t)l * 2048 + hk * 128;
#pragma unroll
        for (int nt = 0; nt < 8; ++nt) {
          const float v1 = o[s][nt][r] * inv;
          dst[nt * 16 + l16] = (__bf16)(v1 - lm * Ex[rr][nt * 16 + l16]);
        }
      }
    }
  }
}

extern "C" void kernel_launch(void* const* d_in, const int* in_sizes, int n_in,
                              void* d_out, int out_size, void* d_ws, size_t ws_size,
                              hipStream_t stream) {
  const float* x     = (const float*)d_in[0];
  const float* W_DKV = (const float*)d_in[1];
  const float* W_UK  = (const float*)d_in[2];
  const float* W_UV  = (const float*)d_in[3];
  const float* W_DQ  = (const float*)d_in[4];
  const float* W_UQ  = (const float*)d_in[5];
  const float* W_lam = (const float*)d_in[6];
  const float* b_lam = (const float*)d_in[7];
  const float* W_out = (const float*)d_in[8];
  float* out = (float*)d_out;

  char* ws = (char*)d_ws;
  #define MB(n) ((size_t)(n) << 20)
  __bf16* x_bf   = (__bf16*)(ws + MB(0));    //  8 MB (2048x2048)
  __bf16* Wt_DKV = (__bf16*)(ws + MB(8));    //  2 MB (512x2048)
  __bf16* Wt_DQ  = (__bf16*)(ws + MB(10));   //  4 MB (1024x2048)
  __bf16* c_kv   = (__bf16*)(ws + MB(14));   //  2 MB (2048x512)
  __bf16* c_q    = (__bf16*)(ws + MB(16));   //  4 MB (2048x1024)
  __bf16* Wt_UK  = (__bf16*)(ws + MB(20));   //  2 MB (2048x512)
  __bf16* Wt_UV  = (__bf16*)(ws + MB(22));   //  2 MB (2048x512)
  __bf16* Wt_UQ  = (__bf16*)(ws + MB(24));   //  8 MB (4096x1024)
  __bf16* k_bf   = (__bf16*)(ws + MB(32));   //  8 MB (2048x2048)
  __bf16* v_bf   = (__bf16*)(ws + MB(40));   //  8 MB (2048x2048)
  __bf16* y_bf   = (__bf16*)(ws + MB(40));   //  8 MB alias: v_bf dead after v_t
  __bf16* q_bf   = (__bf16*)(ws + MB(48));   // 16 MB (2048x4096) un-roped
  __bf16* v_t    = (__bf16*)(ws + MB(64));   //  8 MB (2048x2048)
  float*  lam    = (float*)(ws + MB(88));    // 128 KB
  float*  cosT   = (float*)(ws + MB(89));    //  1 MB
  float*  sinT   = (float*)(ws + MB(90));    //  1 MB
  __bf16* WlT    = (__bf16*)(ws + MB(91));   // 64 KB (16x2048)
  __bf16* Wt_out = (__bf16*)(ws + MB(92));   //  8 MB (2048x2048)  (total 100 MB)

  // one prep launch: 6 weight transposes + x cast + rope tables + W_lam^T
  prep_all<<<18560, 256, 0, stream>>>(W_DKV, W_DQ, W_UK, W_UV, W_UQ, W_out,
                                      x, W_lam,
                                      Wt_DKV, Wt_DQ, Wt_UK, Wt_UV, Wt_UQ, Wt_out,
                                      x_bf, WlT, cosT, sinT);
  // fused down-projections: DKV (4 x-tiles) + DQ (8 x-tiles)
  gemm_fused3<<<dim3(12, 16), 256, 0, stream>>>(
      x_bf, Wt_DKV, c_kv, 512, 2048, 4,
      x_bf, Wt_DQ,  c_q, 1024, 2048, 8,
      x_bf, Wt_DQ,  c_q, 1024, 2048);
  lam_mfma_kernel<<<32, 256, 0, stream>>>(x_bf, WlT, b_lam, lam);
  // fused up-projections: UK (16) + UV (16) + UQ (32)
  gemm_fused3<<<dim3(64, 16), 256, 0, stream>>>(
      c_kv, Wt_UK, k_bf, 2048, 512, 16,
      c_kv, Wt_UV, v_bf, 2048, 512, 16,
      c_q,  Wt_UQ, q_bf, 4096, 1024);
  // K-RoPE + V transpose, one launch
  ropek_transv<<<6144, 256, 0, stream>>>(k_bf, cosT, sinT, v_bf, v_t);
  // flash attention with fused combine -> y_bf
  attn_kernel2<<<512, 256, 0, stream>>>(q_bf, k_bf, v_t, cosT, sinT, lam, y_bf);
  // output projection
  gemm_mfma<false><<<dim3(16, 16), 256, 0, stream>>>(y_bf, Wt_out, out, 2048, 2048, 2048);
}

// Round 9
// 355.699 us; speedup vs baseline: 1.2013x; 1.2013x over previous
//
#include <hip/hip_runtime.h>
#include <cstdint>
#include <cstddef>

typedef __bf16 bf16x8 __attribute__((ext_vector_type(8)));
typedef __bf16 bf16x4 __attribute__((ext_vector_type(4)));
typedef float f32x4 __attribute__((ext_vector_type(4)));

// ---------------------------------------------------------------------------
// Problem constants (B=1): D=2048, NH=16, DH=128, DC=512, DCQ=1024, L=2048
// ---------------------------------------------------------------------------

// ---------------------------------------------------------------------------
// MFMA GEMM core: C(M,N) = A(M,K) @ Bt(N,K)^T.  A,Bt row-major bf16.
// 128x128 tile, BK=32, 4 waves, each wave 64x64 (4x4 of 16x16x32 MFMA).
// ---------------------------------------------------------------------------
template <bool BF16OUT>
__device__ __forceinline__ void gemm_body(const __bf16* __restrict__ A,
                                          const __bf16* __restrict__ Bt,
                                          void* __restrict__ Cv,
                                          int N, int K, int bm, int bn,
                                          __bf16* As, __bf16* Bs) {
  const int tid = threadIdx.x;
  const int w = tid >> 6;
  const int lane = tid & 63;
  const int quad = lane >> 4;
  const int l16 = lane & 15;
  const int wm = (w & 1) * 64;
  const int wn = (w >> 1) * 64;
  const int srow = lane >> 2;
  const int sseg = (lane & 3) * 8;

  f32x4 acc[4][4];
#pragma unroll
  for (int i = 0; i < 4; ++i)
#pragma unroll
    for (int j = 0; j < 4; ++j) acc[i][j] = (f32x4){0.f, 0.f, 0.f, 0.f};

  for (int k0 = 0; k0 < K; k0 += 32) {
    __syncthreads();
#pragma unroll
    for (int g = 0; g < 2; ++g) {
      const int grp = w + g * 4;
      const __bf16* ga = A + (size_t)(bm + grp * 16 + srow) * K + k0 + sseg;
      const __bf16* gb = Bt + (size_t)(bn + grp * 16 + srow) * K + k0 + sseg;
      __builtin_amdgcn_global_load_lds(
          (const __attribute__((address_space(1))) void*)ga,
          (__attribute__((address_space(3))) void*)&As[grp * 512], 16, 0, 0);
      __builtin_amdgcn_global_load_lds(
          (const __attribute__((address_space(1))) void*)gb,
          (__attribute__((address_space(3))) void*)&Bs[grp * 512], 16, 0, 0);
    }
    __syncthreads();
    bf16x8 af[4], bfr[4];
#pragma unroll
    for (int i = 0; i < 4; ++i) {
      af[i] = *(const bf16x8*)&As[(wm + i * 16 + l16) * 32 + quad * 8];
      bfr[i] = *(const bf16x8*)&Bs[(wn + i * 16 + l16) * 32 + quad * 8];
    }
#pragma unroll
    for (int i = 0; i < 4; ++i)
#pragma unroll
      for (int j = 0; j < 4; ++j)
        acc[i][j] = __builtin_amdgcn_mfma_f32_16x16x32_bf16(af[i], bfr[j],
                                                            acc[i][j], 0, 0, 0);
  }
#pragma unroll
  for (int i = 0; i < 4; ++i)
#pragma unroll
    for (int j = 0; j < 4; ++j)
#pragma unroll
      for (int r = 0; r < 4; ++r) {
        const int row = bm + wm + i * 16 + quad * 4 + r;
        const int col = bn + wn + j * 16 + l16;
        if constexpr (BF16OUT)
          ((__bf16*)Cv)[(size_t)row * N + col] = (__bf16)acc[i][j][r];
        else
          ((float*)Cv)[(size_t)row * N + col] = acc[i][j][r];
      }
}

template <bool BF16OUT>
__global__ __launch_bounds__(256) void gemm_mfma(const __bf16* __restrict__ A,
                                                 const __bf16* __restrict__ Bt,
                                                 void* __restrict__ Cv,
                                                 int M, int N, int K) {
  __shared__ __bf16 As[128 * 32];
  __shared__ __bf16 Bs[128 * 32];
  gemm_body<BF16OUT>(A, Bt, Cv, N, K, blockIdx.y * 128, blockIdx.x * 128, As, Bs);
}

// Up to 3 independent GEMMs fused by blockIdx.x ranges.
__global__ __launch_bounds__(256) void gemm_fused3(
    const __bf16* A0, const __bf16* B0, __bf16* C0, int N0, int K0, int nx0,
    const __bf16* A1, const __bf16* B1, __bf16* C1, int N1, int K1, int nx1,
    const __bf16* A2, const __bf16* B2, __bf16* C2, int N2, int K2) {
  __shared__ __bf16 As[128 * 32];
  __shared__ __bf16 Bs[128 * 32];
  const int bx = blockIdx.x;
  const __bf16 *A, *Bt;
  __bf16* C;
  int N, K, bxl;
  if (bx < nx0)            { A = A0; Bt = B0; C = C0; N = N0; K = K0; bxl = bx; }
  else if (bx < nx0 + nx1) { A = A1; Bt = B1; C = C1; N = N1; K = K1; bxl = bx - nx0; }
  else                     { A = A2; Bt = B2; C = C2; N = N2; K = K2; bxl = bx - nx0 - nx1; }
  gemm_body<true>(A, Bt, (void*)C, N, K, blockIdx.y * 128, bxl * 128, As, Bs);
}

// ---------------------------------------------------------------------------
// prep_all: all weight transposes (fp32 (K,N) -> bf16 (N,K), 32x32 tiles),
// x cast, rope tables, W_lam transpose — one launch.
// ---------------------------------------------------------------------------
__global__ __launch_bounds__(256) void prep_all(
    const float* __restrict__ W_DKV, const float* __restrict__ W_DQ,
    const float* __restrict__ W_UK,  const float* __restrict__ W_UV,
    const float* __restrict__ W_UQ,  const float* __restrict__ W_out,
    const float* __restrict__ x,     const float* __restrict__ W_lam,
    __bf16* __restrict__ tDKV, __bf16* __restrict__ tDQ,
    __bf16* __restrict__ tUK,  __bf16* __restrict__ tUV,
    __bf16* __restrict__ tUQ,  __bf16* __restrict__ tOut,
    __bf16* __restrict__ x_bf, __bf16* __restrict__ WlT,
    float* __restrict__ cosT, float* __restrict__ sinT) {
  __shared__ float T[32][36];
  int t = blockIdx.x;
  const int tid = threadIdx.x;
  if (t < 13312) {
    const float* src; __bf16* dst; int K, N, kx, ny;
    if (t < 1024)      {            src = W_DKV; dst = tDKV; K = 2048; N = 512;  kx = t & 63; ny = t >> 6; }
    else if (t < 3072) { t -= 1024; src = W_DQ;  dst = tDQ;  K = 2048; N = 1024; kx = t & 63; ny = t >> 6; }
    else if (t < 4096) { t -= 3072; src = W_UK;  dst = tUK;  K = 512;  N = 2048; kx = t & 15; ny = t >> 4; }
    else if (t < 5120) { t -= 4096; src = W_UV;  dst = tUV;  K = 512;  N = 2048; kx = t & 15; ny = t >> 4; }
    else if (t < 9216) { t -= 5120; src = W_UQ;  dst = tUQ;  K = 1024; N = 4096; kx = t & 31; ny = t >> 5; }
    else               { t -= 9216; src = W_out; dst = tOut; K = 2048; N = 2048; kx = t & 63; ny = t >> 6; }
    const int k0 = kx * 32;
    const int n0 = ny * 32;
    const int r = tid >> 3;
    const int c = (tid & 7) * 4;
    *(float4*)&T[r][c] = *(const float4*)&src[(size_t)(k0 + r) * N + n0 + c];
    __syncthreads();
    bf16x4 o = {(__bf16)T[c + 0][r], (__bf16)T[c + 1][r],
                (__bf16)T[c + 2][r], (__bf16)T[c + 3][r]};
    *(bf16x4*)&dst[(size_t)(n0 + r) * K + k0 + c] = o;
    return;
  }
  t -= 13312;
  if (t < 4096) {  // x cast: 4096 blocks x 1024 floats
    const int i = t * 256 + tid;
    float4 v = *(const float4*)&x[(size_t)i * 4];
    bf16x4 o = {(__bf16)v.x, (__bf16)v.y, (__bf16)v.z, (__bf16)v.w};
    *(bf16x4*)&x_bf[(size_t)i * 4] = o;
    return;
  }
  t -= 4096;
  if (t < 1024) {  // rope tables: 2 rows per block
    const int l = t * 2 + (tid >> 7);
    const int d = tid & 127;
    const int j = d & 63;
    const float inv = exp2f(-(float)j * 0.2076205059304601f);  // log2(1e4)/64
    const float ang = (float)l * inv;
    cosT[l * 128 + d] = cosf(ang);
    sinT[l * 128 + d] = sinf(ang);
    return;
  }
  t -= 1024;
  {  // W_lam (2048,16) -> WlT (16,2048) bf16: 128 blocks
    const int i = t * 256 + tid;
    const int k = i >> 4, n = i & 15;
    WlT[(size_t)n * 2048 + k] = (__bf16)W_lam[i];
  }
}

// ---------------------------------------------------------------------------
// ropek_transv: K-RoPE (in place) + V transpose, one launch.
// ---------------------------------------------------------------------------
__global__ __launch_bounds__(256) void ropek_transv(__bf16* __restrict__ k_bf,
                                                    const float* __restrict__ cosT,
                                                    const float* __restrict__ sinT,
                                                    const __bf16* __restrict__ v_bf,
                                                    __bf16* __restrict__ v_t) {
  __shared__ float row[2048];
  __shared__ __align__(16) __bf16 Ts[32][40];
  int t = blockIdx.x;
  const int tid = threadIdx.x;
  if (t < 2048) {  // rope row t of k_bf (W=2048)
    __bf16* rp = k_bf + (size_t)t * 2048;
#pragma unroll
    for (int i = 0; i < 2; ++i) {
      const int e4 = (tid + 256 * i) * 4;
      bf16x4 v = *(const bf16x4*)&rp[e4];
#pragma unroll
      for (int k = 0; k < 4; ++k) row[e4 + k] = (float)v[k];
    }
    __syncthreads();
#pragma unroll
    for (int i = 0; i < 8; ++i) {
      const int e = tid + 256 * i;
      const int d = e & 127;
      const float c = cosT[t * 128 + d];
      const float s = sinT[t * 128 + d];
      const float tv = row[e];
      const int base = e & ~127;
      const float rot = (d < 64) ? -row[base + d + 64] : row[base + d - 64];
      rp[e] = (__bf16)(tv * c + rot * s);
    }
    return;
  }
  t -= 2048;
  const int l0 = (t & 63) * 32;
  const int d0 = (t >> 6) * 32;
  const int r = tid >> 3;
  const int c = (tid & 7) * 4;
  *(bf16x4*)&Ts[r][c] = *(const bf16x4*)&v_bf[(size_t)(l0 + r) * 2048 + d0 + c];
  __syncthreads();
  bf16x4 o = {Ts[c + 0][r], Ts[c + 1][r], Ts[c + 2][r], Ts[c + 3][r]};
  *(bf16x4*)&v_t[(size_t)(d0 + r) * 2048 + l0 + c] = o;
}

// lam(l,h) = sigmoid(x_bf[l,:] . W_lam[:,h] + b_lam[h]) via MFMA (N=16).
__global__ __launch_bounds__(256) void lam_mfma_kernel(const __bf16* __restrict__ x_bf,
                                                       const __bf16* __restrict__ WlT,
                                                       const float* __restrict__ b_lam,
                                                       float* __restrict__ lam) {
  const int tid = threadIdx.x;
  const int w = tid >> 6, lane = tid & 63, quad = lane >> 4, l16 = lane & 15;
  const int m0 = (blockIdx.x * 4 + w) * 16;
  const __bf16* xrow = x_bf + (size_t)(m0 + l16) * 2048 + quad * 8;
  const __bf16* wrow = WlT + (size_t)l16 * 2048 + quad * 8;
  f32x4 acc[4];
#pragma unroll
  for (int u = 0; u < 4; ++u) acc[u] = (f32x4){0.f, 0.f, 0.f, 0.f};
  for (int k0 = 0; k0 < 2048; k0 += 128) {
#pragma unroll
    for (int u = 0; u < 4; ++u) {
      bf16x8 a = *(const bf16x8*)&xrow[k0 + u * 32];
      bf16x8 b = *(const bf16x8*)&wrow[k0 + u * 32];
      acc[u] = __builtin_amdgcn_mfma_f32_16x16x32_bf16(a, b, acc[u], 0, 0, 0);
    }
  }
  const float bl = b_lam[l16];
#pragma unroll
  for (int r = 0; r < 4; ++r) {
    const float v = acc[0][r] + acc[1][r] + acc[2][r] + acc[3][r] + bl;
    lam[(size_t)(m0 + quad * 4 + r) * 16 + l16] = 1.0f / (1.0f + __expf(-v));
  }
}

// ---------------------------------------------------------------------------
// MFMA flash attention + fused differential combine, LDS-staged K/V.
//  Block = (kv-head hk, 64 q-rows).  Waves 0,1 -> q-head 2hk (rows 0-31,32-63);
//  waves 2,3 -> q-head 2hk+1 same rows (share staged K/V).  K-tile 64.
//  K/V staged via global_load_lds with XOR swizzle (round-7 verified):
//    Ks row r (16 chunks of 16B): stored chunk = c ^ (r&15).
//    Vs row d (8 chunks of 16B):  stored chunk = c ^ (d&7).
//  Q-RoPE + scale fused; P in per-wave LDS (no extra barrier).
//  Epilogue: waves 2,3 publish O2/l2 via LDS; waves 0,1 write
//  y[l, hk*128+d] = O1 - lam*O2 (combine fused, no attn buffer).
// ---------------------------------------------------------------------------
__global__ __launch_bounds__(256, 2) void attn_kernel3(
    const __bf16* __restrict__ Qb, const __bf16* __restrict__ Kb,
    const __bf16* __restrict__ Vt, const float* __restrict__ cosT,
    const float* __restrict__ sinT, const float* __restrict__ lam,
    __bf16* __restrict__ y) {
  __shared__ __align__(16) char smem[51200];
  __bf16* Ks = (__bf16*)smem;                          // 64*128 (16 KB)
  __bf16* Vs = (__bf16*)(smem + 16384);                // 128*64 (16 KB)
  __bf16 (*Ps)[32][72] = (__bf16(*)[32][72])(smem + 32768);  // 18 KB
  float (*Ex)[132] = (float(*)[132])smem;              // epilogue union (33.8 KB)

  const int bx = blockIdx.x;
  const int hv = bx >> 8;
  const int ii = bx & 255;
  const int qt = hv ? (ii >> 4) : 31 - (ii >> 4);  // heavy half first
  const int hk = ii & 15;
  const int q0 = qt * 64;
  const int tid = threadIdx.x;
  const int w = tid >> 6, lane = tid & 63, quad = lane >> 4, l16 = lane & 15;
  const int wrow = (w & 1) * 32;
  const int qoff = (2 * hk + (w >> 1)) * 128;
  const int kvoff = hk * 128;
  const float qscale = 0.08838834764831845f;  // 1/sqrt(128), folded into Q

  // ---- Q fragments + RoPE + scale in-register ----
  bf16x8 aq[2][4];
#pragma unroll
  for (int s = 0; s < 2; ++s) {
    const int l = q0 + wrow + s * 16 + l16;
    const size_t qbase = (size_t)l * 4096 + qoff + quad * 8;
    bf16x8 raw[4];
#pragma unroll
    for (int ks = 0; ks < 4; ++ks)
      raw[ks] = *(const bf16x8*)&Qb[qbase + ks * 32];
#pragma unroll
    for (int ks = 0; ks < 4; ++ks) {
      const float* cp = &cosT[l * 128 + ks * 32 + quad * 8];
      const float* sp = &sinT[l * 128 + ks * 32 + quad * 8];
#pragma unroll
      for (int j = 0; j < 8; ++j) {
        const float cv = cp[j];
        const float sv = sp[j];
        const float rot = (ks < 2) ? -(float)raw[ks + 2][j] : (float)raw[ks - 2][j];
        aq[s][ks][j] = (__bf16)(((float)raw[ks][j] * cv + rot * sv) * qscale);
      }
    }
  }

  f32x4 o[2][8];
#pragma unroll
  for (int s = 0; s < 2; ++s)
#pragma unroll
    for (int i = 0; i < 8; ++i) o[s][i] = (f32x4){0.f, 0.f, 0.f, 0.f};
  float m[2] = {-1e30f, -1e30f}, lsum[2] = {0.f, 0.f};

  for (int kt = 0; kt <= qt; ++kt) {
    const int k0 = kt * 64;
    __syncthreads();  // prev iter's MFMA reads of Ks/Vs done before DMA
    // ---- DMA-stage K (64x128, swizzled) and V^T (128x64, swizzled) ----
#pragma unroll
    for (int d = 0; d < 4; ++d) {
      const int r0 = w * 16 + d * 4;             // 4 K-rows per DMA
      const int row = r0 + (lane >> 4);
      const int ck = (lane & 15) ^ (row & 15);
      const __bf16* ga = Kb + (size_t)(k0 + row) * 2048 + kvoff + ck * 8;
      __builtin_amdgcn_global_load_lds(
          (const __attribute__((address_space(1))) void*)ga,
          (__attribute__((address_space(3))) void*)&Ks[r0 * 128], 16, 0, 0);
      const int r0v = w * 32 + d * 8;            // 8 V-rows per DMA
      const int rowv = r0v + (lane >> 3);
      const int cv = (lane & 7) ^ (rowv & 7);
      const __bf16* gv = Vt + (size_t)(kvoff + rowv) * 2048 + k0 + cv * 8;
      __builtin_amdgcn_global_load_lds(
          (const __attribute__((address_space(1))) void*)gv,
          (__attribute__((address_space(3))) void*)&Vs[r0v * 64], 16, 0, 0);
    }
    __syncthreads();  // drains vmcnt (DMA) per barrier semantics
    // ---- S^T = K Q^T : 4 key m-tiles x 4 k-steps x 2 q-subtiles ----
    f32x4 st[2][4];
#pragma unroll
    for (int s = 0; s < 2; ++s)
#pragma unroll
      for (int t = 0; t < 4; ++t) st[s][t] = (f32x4){0.f, 0.f, 0.f, 0.f};
#pragma unroll
    for (int ks = 0; ks < 4; ++ks) {
#pragma unroll
      for (int t = 0; t < 4; ++t) {
        bf16x8 ak = *(bf16x8*)&Ks[(t * 16 + l16) * 128 + (((ks * 4 + quad) ^ l16) << 3)];
        st[0][t] = __builtin_amdgcn_mfma_f32_16x16x32_bf16(ak, aq[0][ks], st[0][t], 0, 0, 0);
        st[1][t] = __builtin_amdgcn_mfma_f32_16x16x32_bf16(ak, aq[1][ks], st[1][t], 0, 0, 0);
      }
    }
    // ---- online softmax (scale pre-folded into Q) ----
    const bool masked = (kt == qt);
#pragma unroll
    for (int s = 0; s < 2; ++s) {
      const int q = q0 + wrow + s * 16 + l16;
      float rm = -1e30f;
      if (!masked) {
#pragma unroll
        for (int t = 0; t < 4; ++t)
#pragma unroll
          for (int r = 0; r < 4; ++r) rm = fmaxf(rm, st[s][t][r]);
      } else {
#pragma unroll
        for (int t = 0; t < 4; ++t)
#pragma unroll
          for (int r = 0; r < 4; ++r) {
            const int key = k0 + t * 16 + quad * 4 + r;
            if (key > q) st[s][t][r] = -1e30f;
            rm = fmaxf(rm, st[s][t][r]);
          }
      }
      rm = fmaxf(rm, __shfl_xor(rm, 16, 64));
      rm = fmaxf(rm, __shfl_xor(rm, 32, 64));
      const float mn = fmaxf(m[s], rm);
      const float alpha = __expf(m[s] - mn);
      float rs = 0.f;
#pragma unroll
      for (int t = 0; t < 4; ++t)
#pragma unroll
        for (int r = 0; r < 4; ++r) {
          st[s][t][r] = __expf(st[s][t][r] - mn);
          rs += st[s][t][r];
        }
      rs += __shfl_xor(rs, 16, 64);
      rs += __shfl_xor(rs, 32, 64);
      m[s] = mn;
      lsum[s] = lsum[s] * alpha + rs;
#pragma unroll
      for (int t = 0; t < 4; ++t) {
        bf16x4 pk = {(__bf16)st[s][t][0], (__bf16)st[s][t][1],
                     (__bf16)st[s][t][2], (__bf16)st[s][t][3]};
        *(bf16x4*)&Ps[w][s * 16 + l16][t * 16 + quad * 4] = pk;
      }
#pragma unroll
      for (int r = 0; r < 4; ++r) {
        const float ar = __shfl(alpha, quad * 4 + r, 64);
#pragma unroll
        for (int nt = 0; nt < 8; ++nt) o[s][nt][r] *= ar;
      }
    }
    // ---- O += P V : per-wave P (no barrier), each bv feeds 2 MFMAs ----
#pragma unroll
    for (int ks = 0; ks < 2; ++ks) {
      bf16x8 pa0 = *(bf16x8*)&Ps[w][l16][ks * 32 + quad * 8];
      bf16x8 pa1 = *(bf16x8*)&Ps[w][16 + l16][ks * 32 + quad * 8];
#pragma unroll
      for (int nt = 0; nt < 8; ++nt) {
        bf16x8 bv = *(bf16x8*)&Vs[(nt * 16 + l16) * 64 + (((ks * 4 + quad) ^ (l16 & 7)) << 3)];
        o[0][nt] = __builtin_amdgcn_mfma_f32_16x16x32_bf16(pa0, bv, o[0][nt], 0, 0, 0);
        o[1][nt] = __builtin_amdgcn_mfma_f32_16x16x32_bf16(pa1, bv, o[1][nt], 0, 0, 0);
      }
    }
  }
  // ---- epilogue: fused differential combine ----
  __syncthreads();  // all waves done with Ks/Vs/Ps; smem becomes Ex
  if (w >= 2) {     // q-head 2hk+1: publish inv-scaled O
#pragma unroll
    for (int s = 0; s < 2; ++s) {
      const float linv = 1.0f / lsum[s];
#pragma unroll
      for (int r = 0; r < 4; ++r) {
        const float inv = __shfl(linv, quad * 4 + r, 64);
        const int rr = wrow + s * 16 + quad * 4 + r;
#pragma unroll
        for (int nt = 0; nt < 8; ++nt)
          Ex[rr][nt * 16 + l16] = o[s][nt][r] * inv;
      }
    }
  }
  __syncthreads();
  if (w < 2) {      // q-head 2hk: combine and write y
#pragma unroll
    for (int s = 0; s < 2; ++s) {
      const float linv = 1.0f / lsum[s];
#pragma unroll
      for (int r = 0; r < 4; ++r) {
        const float inv = __shfl(linv, quad * 4 + r, 64);
        const int rr = wrow + s * 16 + quad * 4 + r;
        const int l = q0 + rr;
        const float lm = lam[l * 16 + hk];
        __bf16* dst = y + (size_t)l * 2048 + hk * 128;
#pragma unroll
        for (int nt = 0; nt < 8; ++nt) {
          const float v1 = o[s][nt][r] * inv;
          dst[nt * 16 + l16] = (__bf16)(v1 - lm * Ex[rr][nt * 16 + l16]);
        }
      }
    }
  }
}

extern "C" void kernel_launch(void* const* d_in, const int* in_sizes, int n_in,
                              void* d_out, int out_size, void* d_ws, size_t ws_size,
                              hipStream_t stream) {
  const float* x     = (const float*)d_in[0];
  const float* W_DKV = (const float*)d_in[1];
  const float* W_UK  = (const float*)d_in[2];
  const float* W_UV  = (const float*)d_in[3];
  const float* W_DQ  = (const float*)d_in[4];
  const float* W_UQ  = (const float*)d_in[5];
  const float* W_lam = (const float*)d_in[6];
  const float* b_lam = (const float*)d_in[7];
  const float* W_out = (const float*)d_in[8];
  float* out = (float*)d_out;

  char* ws = (char*)d_ws;
  #define MB(n) ((size_t)(n) << 20)
  __bf16* x_bf   = (__bf16*)(ws + MB(0));    //  8 MB (2048x2048)
  __bf16* Wt_DKV = (__bf16*)(ws + MB(8));    //  2 MB (512x2048)
  __bf16* Wt_DQ  = (__bf16*)(ws + MB(10));   //  4 MB (1024x2048)
  __bf16* c_kv   = (__bf16*)(ws + MB(14));   //  2 MB (2048x512)
  __bf16* c_q    = (__bf16*)(ws + MB(16));   //  4 MB (2048x1024)
  __bf16* Wt_UK  = (__bf16*)(ws + MB(20));   //  2 MB (2048x512)
  __bf16* Wt_UV  = (__bf16*)(ws + MB(22));   //  2 MB (2048x512)
  __bf16* Wt_UQ  = (__bf16*)(ws + MB(24));   //  8 MB (4096x1024)
  __bf16* k_bf   = (__bf16*)(ws + MB(32));   //  8 MB (2048x2048)
  __bf16* v_bf   = (__bf16*)(ws + MB(40));   //  8 MB (2048x2048)
  __bf16* y_bf   = (__bf16*)(ws + MB(40));   //  8 MB alias: v_bf dead after v_t
  __bf16* q_bf   = (__bf16*)(ws + MB(48));   // 16 MB (2048x4096) un-roped
  __bf16* v_t    = (__bf16*)(ws + MB(64));   //  8 MB (2048x2048)
  float*  lam    = (float*)(ws + MB(88));    // 128 KB
  float*  cosT   = (float*)(ws + MB(89));    //  1 MB
  float*  sinT   = (float*)(ws + MB(90));    //  1 MB
  __bf16* WlT    = (__bf16*)(ws + MB(91));   // 64 KB (16x2048)
  __bf16* Wt_out = (__bf16*)(ws + MB(92));   //  8 MB (2048x2048)  (total 100 MB)

  // one prep launch: 6 weight transposes + x cast + rope tables + W_lam^T
  prep_all<<<18560, 256, 0, stream>>>(W_DKV, W_DQ, W_UK, W_UV, W_UQ, W_out,
                                      x, W_lam,
                                      Wt_DKV, Wt_DQ, Wt_UK, Wt_UV, Wt_UQ, Wt_out,
                                      x_bf, WlT, cosT, sinT);
  // fused down-projections: DKV (4 x-tiles) + DQ (8 x-tiles)
  gemm_fused3<<<dim3(12, 16), 256, 0, stream>>>(
      x_bf, Wt_DKV, c_kv, 512, 2048, 4,
      x_bf, Wt_DQ,  c_q, 1024, 2048, 8,
      x_bf, Wt_DQ,  c_q, 1024, 2048);
  lam_mfma_kernel<<<32, 256, 0, stream>>>(x_bf, WlT, b_lam, lam);
  // fused up-projections: UK (16) + UV (16) + UQ (32)
  gemm_fused3<<<dim3(64, 16), 256, 0, stream>>>(
      c_kv, Wt_UK, k_bf, 2048, 512, 16,
      c_kv, Wt_UV, v_bf, 2048, 512, 16,
      c_q,  Wt_UQ, q_bf, 4096, 1024);
  // K-RoPE + V transpose, one launch
  ropek_transv<<<6144, 256, 0, stream>>>(k_bf, cosT, sinT, v_bf, v_t);
  // flash attention with LDS-staged K/V + fused combine -> y_bf
  attn_kernel3<<<512, 256, 0, stream>>>(q_bf, k_bf, v_t, cosT, sinT, lam, y_bf);
  // output projection
  gemm_mfma<false><<<dim3(16, 16), 256, 0, stream>>>(y_bf, Wt_out, out, 2048, 2048, 2048);
}